// Round 5
// baseline (488.917 us; speedup 1.0000x reference)
//
#include <hip/hip_runtime.h>
#include <math.h>

#define DIM   1024
#define NV    512
#define VD    256
#define NTOK  32768

// Output layout (floats): out | soft | perp | gumbel
#define SOFT_OFF  8388608u    // 32768*256
#define PERP_OFF  25165824u   // + 32768*512
#define GUM_OFF   25165825u   // + 1  (odd -> only 4B aligned!)

#define LO_SCALE      4096.0f
#define INV_LO_SCALE  (1.0f / 4096.0f)

typedef __attribute__((ext_vector_type(4)))  _Float16 half4;
typedef __attribute__((ext_vector_type(8)))  _Float16 half8;
typedef __attribute__((ext_vector_type(16))) float    float16v;

// d_ws layout: Whi (1MB f16, k-blocked) | Wlo (1MB f16, k-blocked) | sums
#define WLO_ELEM_OFF  (NV * DIM)
#define SUMS_BYTE_OFF (2u * NV * DIM * 2u)

// direct-to-LDS 16B DMA (linear LDS dest = wave-uniform base + lane*16)
#define GLD_LDS16(gp, lp) \
    __builtin_amdgcn_global_load_lds((const __attribute__((address_space(1))) void*)(gp), \
                                     (__attribute__((address_space(3))) void*)(lp), 16, 0, 0)

// ---------------------------------------------------------------------------
// K0: split W (fp32) into f16 hi/lo planes, k-blocked by 8:
//     half index = ((k>>3)*NV + var)*8 + (k&7)
// Step t (BK=16) covers chunks 2t,2t+1; wave wq's slice of a chunk is the
// contiguous 1024-half run at chunk_base + wq*1024.
// ---------------------------------------------------------------------------
__global__ __launch_bounds__(256) void k_wsplit(const float* __restrict__ W,
                                                _Float16* __restrict__ whi,
                                                _Float16* __restrict__ wlo) {
    const int i   = (blockIdx.x * 256 + threadIdx.x) * 4;
    const int var = i >> 10;
    const int k   = i & 1023;
    float4 w = *(const float4*)(W + i);
    _Float16 h0 = (_Float16)w.x, h1 = (_Float16)w.y, h2 = (_Float16)w.z, h3 = (_Float16)w.w;
    _Float16 l0 = (_Float16)((w.x - (float)h0) * LO_SCALE);
    _Float16 l1 = (_Float16)((w.y - (float)h1) * LO_SCALE);
    _Float16 l2 = (_Float16)((w.z - (float)h2) * LO_SCALE);
    _Float16 l3 = (_Float16)((w.w - (float)h3) * LO_SCALE);
    const int dst = ((k >> 3) * NV + var) * 8 + (k & 7);   // k 4-aligned -> one chunk
    *(half4*)(whi + dst) = (half4){h0, h1, h2, h3};
    *(half4*)(wlo + dst) = (half4){l0, l1, l2, l3};
}

// ---------------------------------------------------------------------------
// K1: fused logits(32x512) -> softmax/argmax/one-hot/codebook/colsum.
// Wave-private B staging: each wave double-buffers ONLY its own var slice
// (vars wq*128..+127, hi+lo) in a private 16KB LDS region. No wave reads
// another wave's LDS during the K-loop -> NO __syncthreads in the loop.
// Per-wave sync: one uniform s_waitcnt vmcnt(10) per step (8 DMA + 2 A-loads
// issued per step; the wait drains exactly the previous step's 8 DMAs plus
// the A-pair being consumed, leaving 10 in flight).
// Split-precision f16 math bitwise-identical to the passing kernels.
// ---------------------------------------------------------------------------
#define CVTA(a0_, a1_, ah_, al_) do {                                         \
    float f_[8] = {a0_.x, a0_.y, a0_.z, a0_.w, a1_.x, a1_.y, a1_.z, a1_.w};   \
    _Float16 h_[8], l_[8];                                                    \
    _Pragma("unroll")                                                         \
    for (int j_ = 0; j_ < 8; ++j_) {                                          \
        h_[j_] = (_Float16)f_[j_];                                            \
        l_[j_] = (_Float16)((f_[j_] - (float)h_[j_]) * LO_SCALE);             \
    }                                                                         \
    ah_ = (half8){h_[0], h_[1], h_[2], h_[3], h_[4], h_[5], h_[6], h_[7]};    \
    al_ = (half8){l_[0], l_[1], l_[2], l_[3], l_[4], l_[5], l_[6], l_[7]};    \
} while (0)

#define LOADA(t, a0_, a1_) do {                                               \
    a0_ = *(const float4*)(axp + (size_t)(t) * 16);                           \
    a1_ = *(const float4*)(axp + (size_t)(t) * 16 + 4);                       \
} while (0)

// stage step t's wave-private slice into private buf b: 8 x 16B per lane
// LDS buf layout (halfs): [plane hi 0 / lo 2048][chunk parity *1024][(var-wq*128)*8]
#define STAGE(t, b) do {                                                      \
    const size_t gt_ = (size_t)(t) * 8192 + wq * 1024 + lane * 8;             \
    _Float16*    lb_ = myB + (b) * 4096 + lane * 8;                           \
    GLD_LDS16(whi + gt_,        lb_);                                         \
    GLD_LDS16(whi + gt_ + 512,  lb_ + 512);                                   \
    GLD_LDS16(whi + gt_ + 4096, lb_ + 1024);                                  \
    GLD_LDS16(whi + gt_ + 4608, lb_ + 1536);                                  \
    GLD_LDS16(wlo + gt_,        lb_ + 2048);                                  \
    GLD_LDS16(wlo + gt_ + 512,  lb_ + 2560);                                  \
    GLD_LDS16(wlo + gt_ + 4096, lb_ + 3072);                                  \
    GLD_LDS16(wlo + gt_ + 4608, lb_ + 3584);                                  \
} while (0)

#define KSTEP(b, ah_, al_) do {                                               \
    const _Float16* pb_ = myB + (b) * 4096 + hi * 1024;                       \
    _Pragma("unroll")                                                         \
    for (int p_ = 0; p_ < 4; ++p_) {                                          \
        half8 bh_ = *(const half8*)(pb_ + (p_ * 32 + lm) * 8);                \
        half8 bl_ = *(const half8*)(pb_ + 2048 + (p_ * 32 + lm) * 8);         \
        accM[p_] = __builtin_amdgcn_mfma_f32_32x32x16_f16(ah_, bh_, accM[p_], 0, 0, 0); \
        accC[p_] = __builtin_amdgcn_mfma_f32_32x32x16_f16(ah_, bl_, accC[p_], 0, 0, 0); \
        accC[p_] = __builtin_amdgcn_mfma_f32_32x32x16_f16(al_, bh_, accC[p_], 0, 0, 0); \
    }                                                                         \
} while (0)

__global__ __launch_bounds__(256, 2) void k_fused(
        const float* __restrict__ x,
        const _Float16* __restrict__ whi,
        const _Float16* __restrict__ wlo,
        const float* __restrict__ mask,
        const float* __restrict__ codebook,
        float* __restrict__ soft,
        float* __restrict__ gumbel,
        float* __restrict__ outp,
        float* __restrict__ sums) {
    // 4 waves x private 16KB (2 bufs x [hi 4KB | lo 4KB]) = 64KB
    __shared__ __align__(16) _Float16 sB[32768];
    float* ep = (float*)sB;              // epilogue scratch (aliases, post-loop)

    const int tid  = threadIdx.x;
    const int lane = tid & 63;
    const int wave = tid >> 6;
    const int wq   = wave;               // n-role
    const int lm   = lane & 31;
    const int hi   = lane >> 5;
    const int m0   = blockIdx.x * 32;

    _Float16* myB = sB + wave * 8192;    // private region

    float16v accM[4], accC[4];
#pragma unroll
    for (int p = 0; p < 4; ++p) { accM[p] = (float16v)(0.0f); accC[p] = (float16v)(0.0f); }

    // A: lane reads x[m0 + lm][t*16 + hi*8 .. +7] (hi pair covers full 64B line)
    const float* axp = x + (size_t)(m0 + lm) * DIM + hi * 8;

    float4 pa0, pa1, pb0, pb1;
    half8 ah, al;

    // ---- prologue: 12 VMEM in flight ----
    STAGE(0, 0);                 // 8
    LOADA(0, pa0, pa1);          // 2
    LOADA(1, pb0, pb1);          // 2

    for (int tt = 0; tt < 32; ++tt) {
        const int t0 = tt * 2;
        // ---- even step t0 (buf 0) ----
        STAGE((t0 + 1 < 64) ? t0 + 1 : 63, 1);                  // +8 -> 20
        asm volatile("s_waitcnt vmcnt(10)" ::: "memory");        // drain S(t0)+A(t0)
        __builtin_amdgcn_sched_barrier(0);
        CVTA(pa0, pa1, ah, al);
        { const int tn = (t0 + 2 < 64) ? t0 + 2 : 63; LOADA(tn, pa0, pa1); }  // -> 12
        KSTEP(0, ah, al);
        // ---- odd step t0+1 (buf 1) ----
        STAGE((t0 + 2 < 64) ? t0 + 2 : 63, 0);                  // +8 -> 20
        asm volatile("s_waitcnt vmcnt(10)" ::: "memory");        // drain S(t0+1)+A(t0+1)
        __builtin_amdgcn_sched_barrier(0);
        CVTA(pb0, pb1, ah, al);
        { const int tn = (t0 + 3 < 64) ? t0 + 3 : 63; LOADA(tn, pb0, pb1); }  // -> 12
        KSTEP(1, ah, al);
    }

    // ---------------- fused epilogue (verbatim math from passing kernel) ----------------
    __syncthreads();                       // drains all DMA/loads; sB reusable
    float* smaxA = ep;                     // [4][32]
    float* ssumA = ep + 128;               // [4][32]
    int*   sidxA = (int*)(ep + 256);       // [4][32]
    float* scol  = ep + 384;               // [512]
    int*   skidx = (int*)(ep + 896);       // [32]
    float* smask = ep + 928;               // [32]

    if (tid < 32) smask[tid] = mask[m0 + tid];
    __syncthreads();

    // token row per (r, hi): row = (r&3) + 8*(r>>2) + 4*hi  (32x32 MFMA C-layout)
    int rowv[16];
#pragma unroll
    for (int r = 0; r < 16; ++r) rowv[r] = (r & 3) + 8 * (r >> 2) + 4 * hi;

    float mk[16];
#pragma unroll
    for (int r = 0; r < 16; ++r) mk[r] = smask[rowv[r]];

    // logits + mask + col0 zero
    float v[4][16];
#pragma unroll
    for (int p = 0; p < 4; ++p)
#pragma unroll
        for (int r = 0; r < 16; ++r) {
            float tv = (accM[p][r] + accC[p][r] * INV_LO_SCALE) * mk[r];
            if (wq == 0 && p == 0 && lm == 0) tv = 0.0f;   // var 0
            v[p][r] = tv;
        }

    // argmax (first index on ties): over p in-thread, then butterfly over lm
    float bv[16]; int bi[16];
#pragma unroll
    for (int r = 0; r < 16; ++r) { bv[r] = v[0][r]; bi[r] = wq * 128 + lm; }
#pragma unroll
    for (int p = 1; p < 4; ++p)
#pragma unroll
        for (int r = 0; r < 16; ++r)
            if (v[p][r] > bv[r]) { bv[r] = v[p][r]; bi[r] = wq * 128 + p * 32 + lm; }
#pragma unroll
    for (int off = 16; off >= 1; off >>= 1)
#pragma unroll
        for (int r = 0; r < 16; ++r) {
            float ov = __shfl_xor(bv[r], off, 64);
            int   oi = __shfl_xor(bi[r], off, 64);
            if (ov > bv[r] || (ov == bv[r] && oi < bi[r])) { bv[r] = ov; bi[r] = oi; }
        }
    if (lm == 0)
#pragma unroll
        for (int r = 0; r < 16; ++r) {
            smaxA[wq * 32 + rowv[r]] = bv[r];
            sidxA[wq * 32 + rowv[r]] = bi[r];
        }
    __syncthreads();

    // combine 4 wave-partials (ascending var ranges keep first-index semantics)
    float mx[16]; int kk[16];
#pragma unroll
    for (int r = 0; r < 16; ++r) {
        mx[r] = smaxA[rowv[r]]; kk[r] = sidxA[rowv[r]];
#pragma unroll
        for (int w2 = 1; w2 < 4; ++w2) {
            float mv = smaxA[w2 * 32 + rowv[r]];
            int   iv = sidxA[w2 * 32 + rowv[r]];
            if (mv > mx[r] || (mv == mx[r] && iv < kk[r])) { mx[r] = mv; kk[r] = iv; }
        }
    }

    // exp + row-sum
    float rs[16];
#pragma unroll
    for (int r = 0; r < 16; ++r) rs[r] = 0.0f;
#pragma unroll
    for (int p = 0; p < 4; ++p)
#pragma unroll
        for (int r = 0; r < 16; ++r) {
            v[p][r] = __expf(v[p][r] - mx[r]);
            rs[r] += v[p][r];
        }
#pragma unroll
    for (int off = 16; off >= 1; off >>= 1)
#pragma unroll
        for (int r = 0; r < 16; ++r) rs[r] += __shfl_xor(rs[r], off, 64);
    if (lm == 0)
#pragma unroll
        for (int r = 0; r < 16; ++r) ssumA[wq * 32 + rowv[r]] = rs[r];
    if (wq == 0 && lm == 0)
#pragma unroll
        for (int r = 0; r < 16; ++r) skidx[rowv[r]] = kk[r];
    __syncthreads();

    float inv_[16];
#pragma unroll
    for (int r = 0; r < 16; ++r)
        inv_[r] = 1.0f / (ssumA[rowv[r]] + ssumA[32 + rowv[r]] +
                          ssumA[64 + rowv[r]] + ssumA[96 + rowv[r]]);

    // soft stores + masked column partial sums
    float ca[4] = {0.f, 0.f, 0.f, 0.f};
#pragma unroll
    for (int p = 0; p < 4; ++p)
#pragma unroll
        for (int r = 0; r < 16; ++r) {
            float sv = v[p][r] * inv_[r];
            soft[(size_t)(m0 + rowv[r]) * NV + wq * 128 + p * 32 + lm] = sv;
            ca[p] += sv * mk[r];
        }
#pragma unroll
    for (int p = 0; p < 4; ++p) ca[p] += __shfl_xor(ca[p], 32, 64);
    if (hi == 0)
#pragma unroll
        for (int p = 0; p < 4; ++p) scol[wq * 128 + p * 32 + lm] = ca[p];

    // one-hot + codebook gather (skidx valid since last barrier)
#pragma unroll
    for (int s = 0; s < 8; ++s) {
        const int tk = wq * 8 + s;
        const int k  = skidx[tk];
        float* grow = gumbel + (size_t)(m0 + tk) * NV;   // 4B-aligned base
#pragma unroll
        for (int j = 0; j < 8; ++j)
            grow[j * 64 + lane] = (j * 64 + lane == k) ? 1.0f : 0.0f;
        float4 cv;
        if (k == 0) { cv.x = cv.y = cv.z = cv.w = 0.0f; }
        else        { cv = *(const float4*)(codebook + (size_t)k * VD + lane * 4); }
        *(float4*)(outp + (size_t)(m0 + tk) * VD + lane * 4) = cv;
    }

    __syncthreads();   // scol complete
    atomicAdd(&sums[tid],       scol[tid]);
    atomicAdd(&sums[tid + 256], scol[tid + 256]);
    if (wave == 0) {
        float mv = (lane < 32) ? smask[lane] : 0.0f;
#pragma unroll
        for (int off = 32; off >= 1; off >>= 1) mv += __shfl_xor(mv, off, 64);
        if (lane == 0) atomicAdd(&sums[NV], mv);
    }
}

// ---------------------------------------------------------------------------
// K2: perplexity from 513 accumulated floats
// ---------------------------------------------------------------------------
__global__ __launch_bounds__(256) void k_perp(const float* __restrict__ sums,
                                              float* __restrict__ perp) {
    __shared__ float red[256];
    const int tid = threadIdx.x;
    const float msum = sums[NV];
    float ent = 0.f;
    for (int c = tid; c < NV; c += 256) {
        const float a = sums[c] / msum;
        ent += a * logf(a + 1e-7f);
    }
    red[tid] = ent;
    __syncthreads();
    for (int s = 128; s > 0; s >>= 1) {
        if (tid < s) red[tid] += red[tid + s];
        __syncthreads();
    }
    if (tid == 0) perp[0] = expf(-red[0]);
}

// ---------------------------------------------------------------------------
extern "C" void kernel_launch(void* const* d_in, const int* in_sizes, int n_in,
                              void* d_out, int out_size, void* d_ws, size_t ws_size,
                              hipStream_t stream) {
    const float* x    = (const float*)d_in[0];
    const float* mask = (const float*)d_in[1];
    const float* W    = (const float*)d_in[2];
    const float* cb   = (const float*)d_in[3];

    float* out    = (float*)d_out;
    float* soft   = out + SOFT_OFF;
    float* perp   = out + PERP_OFF;
    float* gumbel = out + GUM_OFF;

    _Float16* whi = (_Float16*)d_ws;
    _Float16* wlo = whi + WLO_ELEM_OFF;
    float* sums   = (float*)((char*)d_ws + SUMS_BYTE_OFF);

    hipMemsetAsync(sums, 0, (NV + 1) * sizeof(float), stream);

    k_wsplit<<<NV * DIM / (256 * 4), 256, 0, stream>>>(W, whi, wlo);
    k_fused<<<NTOK / 32, 256, 0, stream>>>(x, whi, wlo, mask, cb, soft, gumbel, out, sums);
    k_perp<<<1, 256, 0, stream>>>(sums, perp);
}

// Round 6
// 415.790 us; speedup vs baseline: 1.1759x; 1.1759x over previous
//
#include <hip/hip_runtime.h>
#include <math.h>

#define DIM   1024
#define NV    512
#define VD    256
#define NTOK  32768

// Output layout (floats): out | soft | perp | gumbel
#define SOFT_OFF  8388608u    // 32768*256
#define PERP_OFF  25165824u   // + 32768*512
#define GUM_OFF   25165825u   // + 1  (odd -> only 4B aligned!)

#define LO_SCALE      4096.0f
#define INV_LO_SCALE  (1.0f / 4096.0f)

typedef __attribute__((ext_vector_type(4)))  _Float16 half4;
typedef __attribute__((ext_vector_type(8)))  _Float16 half8;
typedef __attribute__((ext_vector_type(16))) float    float16v;

// d_ws layout: Whi (1MB f16, k-blocked) | Wlo (1MB f16, k-blocked) | sums
#define WLO_ELEM_OFF  (NV * DIM)
#define SUMS_BYTE_OFF (2u * NV * DIM * 2u)

// direct-to-LDS 16B DMA (linear LDS dest = wave-uniform base + lane*16)
#define GLD_LDS16(gp, lp) \
    __builtin_amdgcn_global_load_lds((const __attribute__((address_space(1))) void*)(gp), \
                                     (__attribute__((address_space(3))) void*)(lp), 16, 0, 0)

// ---------------------------------------------------------------------------
// K0: split W (fp32) into f16 hi/lo planes, k-blocked by 8:
//     half index = ((k>>3)*NV + var)*8 + (k&7)
// Step t (BK=32) covers chunks 4t..4t+3 = one contiguous 32KB slab per plane.
// ---------------------------------------------------------------------------
__global__ __launch_bounds__(256) void k_wsplit(const float* __restrict__ W,
                                                _Float16* __restrict__ whi,
                                                _Float16* __restrict__ wlo) {
    const int i   = (blockIdx.x * 256 + threadIdx.x) * 4;
    const int var = i >> 10;
    const int k   = i & 1023;
    float4 w = *(const float4*)(W + i);
    _Float16 h0 = (_Float16)w.x, h1 = (_Float16)w.y, h2 = (_Float16)w.z, h3 = (_Float16)w.w;
    _Float16 l0 = (_Float16)((w.x - (float)h0) * LO_SCALE);
    _Float16 l1 = (_Float16)((w.y - (float)h1) * LO_SCALE);
    _Float16 l2 = (_Float16)((w.z - (float)h2) * LO_SCALE);
    _Float16 l3 = (_Float16)((w.w - (float)h3) * LO_SCALE);
    const int dst = ((k >> 3) * NV + var) * 8 + (k & 7);   // k 4-aligned -> one chunk
    *(half4*)(whi + dst) = (half4){h0, h1, h2, h3};
    *(half4*)(wlo + dst) = (half4){l0, l1, l2, l3};
}

// ---------------------------------------------------------------------------
// K1: fused logits(64x512) -> softmax/argmax/one-hot/codebook/colsum.
// BM=64, 8 waves: wave w -> m-half mh=w>>2 (tokens tb..tb+31), n-quarter
// wq=w&3 (vars wq*128..+127). BK=32. B hi/lo double-buffered in 128KB LDS
// via global_load_lds (linear dest, wave w stages its plane/quarter slice).
// R2's twice-passed sync structure: DMA for step t+1 issued at top of step t,
// drained by the plain __syncthreads at the end of step t (a full 24-MFMA
// compute phase of latency cover). A per-lane direct from x into registers.
// Split-precision f16 math bitwise-identical to the passing kernels.
// ---------------------------------------------------------------------------
#define CVTA(a0_, a1_, ah_, al_) do {                                         \
    float f_[8] = {a0_.x, a0_.y, a0_.z, a0_.w, a1_.x, a1_.y, a1_.z, a1_.w};   \
    _Float16 h_[8], l_[8];                                                    \
    _Pragma("unroll")                                                         \
    for (int j_ = 0; j_ < 8; ++j_) {                                          \
        h_[j_] = (_Float16)f_[j_];                                            \
        l_[j_] = (_Float16)((f_[j_] - (float)h_[j_]) * LO_SCALE);             \
    }                                                                         \
    ah_ = (half8){h_[0], h_[1], h_[2], h_[3], h_[4], h_[5], h_[6], h_[7]};    \
    al_ = (half8){l_[0], l_[1], l_[2], l_[3], l_[4], l_[5], l_[6], l_[7]};    \
} while (0)

// wave stages its plane's quarter of step t's 32KB slab: 8 x 16B per lane
#define STAGE(t_, b_) do {                                                    \
    const _Float16* g_ = gS + (size_t)(t_) * 16384;                           \
    _Float16*       l_ = lS + (b_) * 32768;                                   \
    GLD_LDS16(g_,        l_);                                                 \
    GLD_LDS16(g_ + 512,  l_ + 512);                                           \
    GLD_LDS16(g_ + 1024, l_ + 1024);                                          \
    GLD_LDS16(g_ + 1536, l_ + 1536);                                          \
    GLD_LDS16(g_ + 2048, l_ + 2048);                                          \
    GLD_LDS16(g_ + 2560, l_ + 2560);                                          \
    GLD_LDS16(g_ + 3072, l_ + 3072);                                          \
    GLD_LDS16(g_ + 3584, l_ + 3584);                                          \
} while (0)

// one 16-k half-step: chunk = kk*2 + hi; var = wq*128 + p*32 + lm
#define KSTEP(b_, kk_, ah_, al_) do {                                         \
    const _Float16* pb_ = sB + (b_) * 32768 + ((kk_) * 2 + hi) * 4096         \
                             + wq * 1024 + lm * 8;                            \
    _Pragma("unroll")                                                         \
    for (int p_ = 0; p_ < 4; ++p_) {                                          \
        half8 bh_ = *(const half8*)(pb_ + p_ * 256);                          \
        half8 bl_ = *(const half8*)(pb_ + 16384 + p_ * 256);                  \
        accM[p_] = __builtin_amdgcn_mfma_f32_32x32x16_f16(ah_, bh_, accM[p_], 0, 0, 0); \
        accC[p_] = __builtin_amdgcn_mfma_f32_32x32x16_f16(ah_, bl_, accC[p_], 0, 0, 0); \
        accC[p_] = __builtin_amdgcn_mfma_f32_32x32x16_f16(al_, bh_, accC[p_], 0, 0, 0); \
    }                                                                         \
} while (0)

__global__ __launch_bounds__(512, 2) void k_fused(
        const float* __restrict__ x,
        const _Float16* __restrict__ whi,
        const _Float16* __restrict__ wlo,
        const float* __restrict__ mask,
        const float* __restrict__ codebook,
        float* __restrict__ soft,
        float* __restrict__ gumbel,
        float* __restrict__ outp,
        float* __restrict__ sums) {
    // [2 buf][ hi: 4 chunks x 512 var x 8 | lo: same ] halfs = 128KB
    __shared__ __align__(16) _Float16 sB[65536];
    float* ep = (float*)sB;              // epilogue scratch (aliases, post-loop)

    const int tid  = threadIdx.x;
    const int lane = tid & 63;
    const int wave = tid >> 6;
    const int lm   = lane & 31;
    const int hi   = lane >> 5;
    const int wq   = wave & 3;           // n-quarter
    const int mh   = wave >> 2;          // m-half
    const int m0   = blockIdx.x * 64;
    const int tb   = m0 + mh * 32;       // this wave's token base

    float16v accM[4], accC[4];
#pragma unroll
    for (int p = 0; p < 4; ++p) { accM[p] = (float16v)(0.0f); accC[p] = (float16v)(0.0f); }

    // A: lane reads x[tb + lm][t*32 + kk*16 + hi*8 .. +7]
    const float* axp = x + (size_t)(tb + lm) * DIM + hi * 8;

    // B staging: wave w -> plane (w>=4 ? lo : hi), quarter wq (4096 halfs/step)
    const _Float16* gS = ((wave >= 4) ? wlo : whi) + (size_t)(wq * 4096 + lane * 8);
    _Float16*       lS = sB + ((wave >= 4) ? 16384 : 0) + wq * 4096 + lane * 8;

    float4 a00, a01, a10, a11;
    a00 = *(const float4*)(axp);      a01 = *(const float4*)(axp + 4);
    a10 = *(const float4*)(axp + 16); a11 = *(const float4*)(axp + 20);
    STAGE(0, 0);
    __syncthreads();   // buf0 ready

    for (int t = 0; t < 32; ++t) {
        const int buf = t & 1;
        if (t < 31) STAGE(t + 1, buf ^ 1);   // drained by this step's end barrier
        half8 ah, al;
        CVTA(a00, a01, ah, al);
        KSTEP(buf, 0, ah, al);
        if (t < 31) {
            const size_t o = (size_t)(t + 1) * 32;
            a00 = *(const float4*)(axp + o); a01 = *(const float4*)(axp + o + 4);
        }
        CVTA(a10, a11, ah, al);
        KSTEP(buf, 1, ah, al);
        if (t < 31) {
            const size_t o = (size_t)(t + 1) * 32 + 16;
            a10 = *(const float4*)(axp + o); a11 = *(const float4*)(axp + o + 4);
        }
        __syncthreads();
    }

    // ---------------- fused epilogue (per 32-token half; math verbatim) ----------------
    __syncthreads();                       // sB reusable
    float* epH   = ep + mh * 960;
    float* smaxA = epH;                    // [4][32]
    float* ssumA = epH + 128;              // [4][32]
    int*   sidxA = (int*)(epH + 256);      // [4][32]
    float* scol  = epH + 384;              // [512]
    int*   skidx = (int*)(epH + 896);      // [32]
    float* smask = epH + 928;              // [32]

    if (wq == 0 && lane < 32) smask[lane] = mask[tb + lane];
    __syncthreads();

    // token row per (r, hi): row = (r&3) + 8*(r>>2) + 4*hi  (32x32 MFMA C-layout)
    int rowv[16];
#pragma unroll
    for (int r = 0; r < 16; ++r) rowv[r] = (r & 3) + 8 * (r >> 2) + 4 * hi;

    float mk[16];
#pragma unroll
    for (int r = 0; r < 16; ++r) mk[r] = smask[rowv[r]];

    // logits + mask + col0 zero
    float v[4][16];
#pragma unroll
    for (int p = 0; p < 4; ++p)
#pragma unroll
        for (int r = 0; r < 16; ++r) {
            float tv = (accM[p][r] + accC[p][r] * INV_LO_SCALE) * mk[r];
            if (wq == 0 && p == 0 && lm == 0) tv = 0.0f;   // var 0
            v[p][r] = tv;
        }

    // argmax (first index on ties): over p in-thread, then butterfly over lm
    float bv[16]; int bi[16];
#pragma unroll
    for (int r = 0; r < 16; ++r) { bv[r] = v[0][r]; bi[r] = wq * 128 + lm; }
#pragma unroll
    for (int p = 1; p < 4; ++p)
#pragma unroll
        for (int r = 0; r < 16; ++r)
            if (v[p][r] > bv[r]) { bv[r] = v[p][r]; bi[r] = wq * 128 + p * 32 + lm; }
#pragma unroll
    for (int off = 16; off >= 1; off >>= 1)
#pragma unroll
        for (int r = 0; r < 16; ++r) {
            float ov = __shfl_xor(bv[r], off, 64);
            int   oi = __shfl_xor(bi[r], off, 64);
            if (ov > bv[r] || (ov == bv[r] && oi < bi[r])) { bv[r] = ov; bi[r] = oi; }
        }
    if (lm == 0)
#pragma unroll
        for (int r = 0; r < 16; ++r) {
            smaxA[wq * 32 + rowv[r]] = bv[r];
            sidxA[wq * 32 + rowv[r]] = bi[r];
        }
    __syncthreads();

    // combine 4 wave-partials (ascending var ranges keep first-index semantics)
    float mx[16]; int kk[16];
#pragma unroll
    for (int r = 0; r < 16; ++r) {
        mx[r] = smaxA[rowv[r]]; kk[r] = sidxA[rowv[r]];
#pragma unroll
        for (int w2 = 1; w2 < 4; ++w2) {
            float mv = smaxA[w2 * 32 + rowv[r]];
            int   iv = sidxA[w2 * 32 + rowv[r]];
            if (mv > mx[r] || (mv == mx[r] && iv < kk[r])) { mx[r] = mv; kk[r] = iv; }
        }
    }

    // exp + row-sum
    float rs[16];
#pragma unroll
    for (int r = 0; r < 16; ++r) rs[r] = 0.0f;
#pragma unroll
    for (int p = 0; p < 4; ++p)
#pragma unroll
        for (int r = 0; r < 16; ++r) {
            v[p][r] = __expf(v[p][r] - mx[r]);
            rs[r] += v[p][r];
        }
#pragma unroll
    for (int off = 16; off >= 1; off >>= 1)
#pragma unroll
        for (int r = 0; r < 16; ++r) rs[r] += __shfl_xor(rs[r], off, 64);
    if (lm == 0)
#pragma unroll
        for (int r = 0; r < 16; ++r) ssumA[wq * 32 + rowv[r]] = rs[r];
    if (wq == 0 && lm == 0)
#pragma unroll
        for (int r = 0; r < 16; ++r) skidx[rowv[r]] = kk[r];
    __syncthreads();

    float inv_[16];
#pragma unroll
    for (int r = 0; r < 16; ++r)
        inv_[r] = 1.0f / (ssumA[rowv[r]] + ssumA[32 + rowv[r]] +
                          ssumA[64 + rowv[r]] + ssumA[96 + rowv[r]]);

    // soft stores + masked column partial sums
    float ca[4] = {0.f, 0.f, 0.f, 0.f};
#pragma unroll
    for (int p = 0; p < 4; ++p)
#pragma unroll
        for (int r = 0; r < 16; ++r) {
            float sv = v[p][r] * inv_[r];
            soft[(size_t)(tb + rowv[r]) * NV + wq * 128 + p * 32 + lm] = sv;
            ca[p] += sv * mk[r];
        }
#pragma unroll
    for (int p = 0; p < 4; ++p) ca[p] += __shfl_xor(ca[p], 32, 64);
    if (hi == 0)
#pragma unroll
        for (int p = 0; p < 4; ++p) scol[wq * 128 + p * 32 + lm] = ca[p];

    // one-hot + codebook gather (skidx valid since last barrier)
#pragma unroll
    for (int s = 0; s < 8; ++s) {
        const int tk = wq * 8 + s;
        const int k  = skidx[tk];
        float* grow = gumbel + (size_t)(tb + tk) * NV;   // 4B-aligned base
#pragma unroll
        for (int j = 0; j < 8; ++j)
            grow[j * 64 + lane] = (j * 64 + lane == k) ? 1.0f : 0.0f;
        float4 cv;
        if (k == 0) { cv.x = cv.y = cv.z = cv.w = 0.0f; }
        else        { cv = *(const float4*)(codebook + (size_t)k * VD + lane * 4); }
        *(float4*)(outp + (size_t)(tb + tk) * VD + lane * 4) = cv;
    }

    __syncthreads();   // both halves' scol complete
    atomicAdd(&sums[tid], ep[384 + tid] + ep[1344 + tid]);   // half0 + half1 col sums
    if (wave == 0) {
        float mv = (lane < 32) ? (ep[928 + lane] + ep[1888 + lane]) : 0.0f;
#pragma unroll
        for (int off = 32; off >= 1; off >>= 1) mv += __shfl_xor(mv, off, 64);
        if (lane == 0) atomicAdd(&sums[NV], mv);
    }
}

// ---------------------------------------------------------------------------
// K2: perplexity from 513 accumulated floats
// ---------------------------------------------------------------------------
__global__ __launch_bounds__(256) void k_perp(const float* __restrict__ sums,
                                              float* __restrict__ perp) {
    __shared__ float red[256];
    const int tid = threadIdx.x;
    const float msum = sums[NV];
    float ent = 0.f;
    for (int c = tid; c < NV; c += 256) {
        const float a = sums[c] / msum;
        ent += a * logf(a + 1e-7f);
    }
    red[tid] = ent;
    __syncthreads();
    for (int s = 128; s > 0; s >>= 1) {
        if (tid < s) red[tid] += red[tid + s];
        __syncthreads();
    }
    if (tid == 0) perp[0] = expf(-red[0]);
}

// ---------------------------------------------------------------------------
extern "C" void kernel_launch(void* const* d_in, const int* in_sizes, int n_in,
                              void* d_out, int out_size, void* d_ws, size_t ws_size,
                              hipStream_t stream) {
    const float* x    = (const float*)d_in[0];
    const float* mask = (const float*)d_in[1];
    const float* W    = (const float*)d_in[2];
    const float* cb   = (const float*)d_in[3];

    float* out    = (float*)d_out;
    float* soft   = out + SOFT_OFF;
    float* perp   = out + PERP_OFF;
    float* gumbel = out + GUM_OFF;

    _Float16* whi = (_Float16*)d_ws;
    _Float16* wlo = whi + WLO_ELEM_OFF;
    float* sums   = (float*)((char*)d_ws + SUMS_BYTE_OFF);

    hipMemsetAsync(sums, 0, (NV + 1) * sizeof(float), stream);

    k_wsplit<<<NV * DIM / (256 * 4), 256, 0, stream>>>(W, whi, wlo);
    k_fused<<<NTOK / 64, 512, 0, stream>>>(x, whi, wlo, mask, cb, soft, gumbel, out, sums);
    k_perp<<<1, 256, 0, stream>>>(sums, perp);
}